// Round 23
// baseline (128.800 us; speedup 1.0000x reference)
//
#include <hip/hip_runtime.h>
#include <stdint.h>

#define BB 4
#define NN 32768
#define PRE 4096
#define POST 512
#define NMS_TH 0.7f
#define MIDCAP 8192
#define BGRID 18          // spatial hash: 18x18 bins of width 4 over [0,72]
#define BINS (BGRID * BGRID)
#define BCAP2 64          // entries per bin in threat kernel (overflow -> sentinel)
#define TCAP 15           // threats per box in a 32B pack (overflow -> sentinel)

typedef unsigned long long u64;
typedef unsigned int u32;
typedef unsigned short u16;

__device__ __forceinline__ u32 orderable(float f) {
  u32 u = __float_as_uint(f);
  return (u & 0x80000000u) ? ~u : (u | 0x80000000u);
}
__device__ __forceinline__ float unorderable(u32 o) {
  u32 u = (o & 0x80000000u) ? (o & 0x7fffffffu) : ~o;
  return __uint_as_float(u);
}
// Monotone fixed-point bucket: uniform in score space (scores in [0,1)).
__device__ __forceinline__ u32 bucket_of(float s) {
  u32 v = (u32)(s * 2147483648.0f);
  u32 bk = v >> 20;
  return bk > 2047u ? 2047u : bk;
}
__device__ __forceinline__ u64 readlane64(u64 v, int l) {
  u32 lo = (u32)__builtin_amdgcn_readlane((int)(u32)v, l);
  u32 hi = (u32)__builtin_amdgcn_readlane((int)(u32)(v >> 32), l);
  return ((u64)hi << 32) | lo;
}
// IoU fast compare (threshold form) with margin tracking; exact-divide twin.
// Same op order as reference: denom = ((a1 + a2) - inter) + 1e-6.
__device__ __forceinline__ bool iou_fast(float4 a, float aa, float4 b, float ba, float& mm) {
  float ix = fminf(a.z, b.z) - fmaxf(a.x, b.x); ix = fmaxf(0.0f, ix);
  float iy = fminf(a.w, b.w) - fmaxf(a.y, b.y); iy = fmaxf(0.0f, iy);
  float inter = ix * iy;
  float denom = ((aa + ba) - inter) + 1e-6f;
  float t = 0.7f * denom;
  mm = fminf(mm, fabsf(inter - t) - 2e-5f * t);   // band >> max rounding skew (~4e-7)
  return inter > t;
}
__device__ __forceinline__ bool iou_exact(float4 a, float aa, float4 b, float ba) {
  float ix = fminf(a.z, b.z) - fmaxf(a.x, b.x); ix = fmaxf(0.0f, ix);
  float iy = fminf(a.w, b.w) - fmaxf(a.y, b.y); iy = fmaxf(0.0f, iy);
  float inter = ix * iy;
  float denom = ((aa + ba) - inter) + 1e-6f;
  return (inter / denom) > NMS_TH;
}
// Exact pair decision (fast path + per-pair exact-divide redo when marginal).
__device__ __forceinline__ bool iou_pair(float4 a, float aa, float4 b, float ba) {
  float mmp = 1.0f;
  bool h = iou_fast(a, aa, b, ba, mmp);
  if (mmp <= 0.0f) h = iou_exact(a, aa, b, ba);
  return h;
}
__device__ __forceinline__ int bin_coord(float c) {
  int v = (int)(c * 0.25f);
  return v < 0 ? 0 : (v > BGRID - 1 ? BGRID - 1 : v);
}

// score/label/key for 4 points per thread (vectorized). Per-block PARTIAL
// histogram with plain stores — no global atomics, no pre-zero, no fence.
__global__ __launch_bounds__(256) void score_hist_kernel(const float* __restrict__ cls,
                                                         int* __restrict__ labels,
                                                         u64* __restrict__ keys,
                                                         u32* __restrict__ histP) {
  __shared__ u32 lh[2048];
  for (int t = threadIdx.x; t < 2048; t += 256) lh[t] = 0;
  __syncthreads();
  int t4 = blockIdx.x * 256 + threadIdx.x;
  int base4 = t4 * 4;                               // first point id (batches 4-aligned)
  const float4* c4 = (const float4*)(cls + (size_t)t4 * 12);
  float4 va = c4[0], vb = c4[1], vc = c4[2];
  float v[12] = {va.x, va.y, va.z, va.w, vb.x, vb.y, vb.z, vb.w, vc.x, vc.y, vc.z, vc.w};
  u64 ks[4]; int ls[4];
#pragma unroll
  for (int p = 0; p < 4; ++p) {
    float s = v[3 * p]; int l = 0;
    if (v[3 * p + 1] > s) { s = v[3 * p + 1]; l = 1; }
    if (v[3 * p + 2] > s) { s = v[3 * p + 2]; l = 2; }
    int n = (base4 + p) & (NN - 1);
    ks[p] = ((u64)orderable(s) << 32) | (u32)(~(u32)n);
    ls[p] = l;
    atomicAdd(&lh[bucket_of(s)], 1u);
  }
  *(ulonglong2*)(keys + base4) = make_ulonglong2(ks[0], ks[1]);
  *(ulonglong2*)(keys + base4 + 2) = make_ulonglong2(ks[2], ks[3]);
  *(int4*)(labels + base4) = make_int4(ls[0], ls[1], ls[2], ls[3]);
  __syncthreads();
  u32* myrow = histP + (size_t)blockIdx.x * 2048;
  for (int t = threadIdx.x; t < 2048; t += 256) myrow[t] = lh[t];
}

// Per batch: sum the 32 partial histograms, suffix-scan, find threshold bucket
// T, init per-bucket cursors. Zeroes this batch's mid counter and maxW.
__global__ __launch_bounds__(256) void select_kernel(const u32* __restrict__ histP,
                                                     u32* __restrict__ selinfo,
                                                     u32* __restrict__ sfxBuf,
                                                     u32* __restrict__ cursor,
                                                     u32* __restrict__ cnt_mid,
                                                     u32* __restrict__ maxWG) {
  __shared__ u32 sfx[2048];
  int b = blockIdx.x;
  if (threadIdx.x == 0) { cnt_mid[b] = 0; maxWG[b] = 0; }
  for (int t = threadIdx.x; t < 2048; t += 256) {
    u32 s = 0;
    const u32* pp = histP + (size_t)(b * 32) * 2048 + t;
#pragma unroll
    for (int j = 0; j < 32; ++j) s += pp[(size_t)j * 2048];
    sfx[t] = s;
  }
  __syncthreads();
  for (int d = 1; d < 2048; d <<= 1) {
    u32 v[8];
#pragma unroll
    for (int i = 0; i < 8; ++i) {
      int t = threadIdx.x + i * 256;
      v[i] = (t + d < 2048) ? sfx[t + d] : 0;
    }
    __syncthreads();
#pragma unroll
    for (int i = 0; i < 8; ++i) sfx[threadIdx.x + i * 256] += v[i];
    __syncthreads();
  }
  for (int t = threadIdx.x; t < 2048; t += 256) {
    u32 above = (t + 1 < 2048) ? sfx[t + 1] : 0;
    sfxBuf[b * 2048 + t] = sfx[t];
    cursor[b * 2048 + t] = above;                       // segment base
    if (above < PRE && sfx[t] >= PRE) { selinfo[b * 2] = (u32)t; selinfo[b * 2 + 1] = above; }
  }
}

// Compact, 4 keys/thread (2x ulonglong2 loads): hi keys scatter into their
// bucket's segment via per-bucket cursors; mid keys to the tie-break buffer.
__global__ __launch_bounds__(256) void compact_kernel(const u64* __restrict__ keys,
                                                      const u32* __restrict__ selinfo,
                                                      u32* __restrict__ cursor,
                                                      u64* __restrict__ sel, u64* __restrict__ mid,
                                                      u32* __restrict__ cnt_mid) {
  int t4 = blockIdx.x * 256 + threadIdx.x;
  int base4 = t4 * 4;
  int b = base4 >> 15;
  u32 T = selinfo[b * 2];
  ulonglong2 k01 = *(const ulonglong2*)(keys + base4);
  ulonglong2 k23 = *(const ulonglong2*)(keys + base4 + 2);
  u64 kk[4] = {k01.x, k01.y, k23.x, k23.y};
#pragma unroll
  for (int p = 0; p < 4; ++p) {
    u64 key = kk[p];
    u32 bk = bucket_of(unorderable((u32)(key >> 32)));
    if (bk > T) {
      u32 q = atomicAdd(&cursor[b * 2048 + bk], 1u);
      sel[((size_t)b << 12) + q] = key;
    } else if (bk == T) {
      u32 q = atomicAdd(&cnt_mid[b], 1u);
      if (q < MIDCAP) mid[(size_t)b * MIDCAP + q] = key;   // ~45 expected with this data
    }
  }
}

// One wave per (batch, bucket). Buckets > T: in-register 64-lane bitonic sort.
// Bucket == T: fused midsel. Then fused gather of P/AR/topS; tracks the max
// box extent (atomicMax) for the spatial-hash reach.
__global__ __launch_bounds__(64) void bsort_kernel(u64* __restrict__ sel, u64* __restrict__ mid,
                                                   const u32* __restrict__ sfxBuf,
                                                   const u32* __restrict__ selinfo,
                                                   const u32* __restrict__ cnt_mid,
                                                   const float* __restrict__ boxes,
                                                   float4* __restrict__ P,
                                                   float* __restrict__ AR,
                                                   float* __restrict__ topS,
                                                   u32* __restrict__ maxWG) {
  int t = blockIdx.x & 2047;
  int b = blockIdx.x >> 11;
  int lane = threadIdx.x;
  u32 T = selinfo[b * 2];
  if ((u32)t < T) return;
  u64* selB = sel + ((size_t)b << 12);
  u32 start, end;
  if ((u32)t == T) {
    u32 C1 = selinfo[b * 2 + 1];
    int need = PRE - (int)C1;
    int M = (int)cnt_mid[b]; if (M > MIDCAP) M = MIDCAP;
    u64* midB = mid + (size_t)b * MIDCAP;
    for (int r = 0; r < need; ++r) {
      u64 best = 0; int bi = -1;
      for (int q = lane; q < M; q += 64) {
        u64 v = midB[q];
        if (v > best) { best = v; bi = q; }
      }
#pragma unroll
      for (int d = 32; d > 0; d >>= 1) {
        u64 ob = __shfl_xor(best, d, 64);
        int oi = __shfl_xor(bi, d, 64);
        if (ob > best) { best = ob; bi = oi; }
      }
      if (lane == 0) selB[C1 + r] = best;
      if (bi >= 0 && lane == (bi & 63)) midB[bi] = 0;    // remove chosen
    }
    start = C1; end = PRE;
  } else {
    start = (t < 2047) ? sfxBuf[b * 2048 + t + 1] : 0u;
    end = sfxBuf[b * 2048 + t];
    int n = (int)(end - start);
    if (n > 64) {
      // robustness fallback (never hit on bench data): selection sort
      for (int r = 0; r < n - 1; ++r) {
        u64 best = 0; int bi = -1;
        for (int q = r + lane; q < n; q += 64) {
          u64 v = selB[start + q];
          if (v > best) { best = v; bi = q; }
        }
#pragma unroll
        for (int d = 32; d > 0; d >>= 1) {
          u64 ob = __shfl_xor(best, d, 64);
          int oi = __shfl_xor(bi, d, 64);
          if (ob > best) { best = ob; bi = oi; }
        }
        if (lane == 0) {
          u64 tmp = selB[start + r];
          selB[start + r] = best;
          selB[start + bi] = tmp;
        }
      }
    } else if (n > 1) {
      u64 v = (lane < n) ? selB[start + lane] : 0ULL;    // MSB-set keys: pad sinks
#pragma unroll
      for (int k = 2; k <= 64; k <<= 1) {
#pragma unroll
        for (int j = k >> 1; j > 0; j >>= 1) {
          u64 o = __shfl_xor(v, j, 64);
          bool up = ((lane & k) == 0);
          bool first = ((lane & j) == 0);
          u64 mx = v > o ? v : o, mn = v > o ? o : v;
          v = (first == up) ? mx : mn;
        }
      }
      if (lane < n) selB[start + lane] = v;
    }
  }
  __builtin_amdgcn_s_waitcnt(0);                         // selB writes visible to this wave
  // ---- fused gather (P/AR/topS) + max-extent tracking for [start, end) ----
  float wmax = 0.0f;
  for (u32 pos = start + lane; pos < end; pos += 64) {
    u64 key = selB[pos];
    u32 n = ~(u32)key;
    const float* bx = boxes + ((size_t)b * NN + n) * 7;
    float x = bx[0], y = bx[1], dx = bx[3], dy = bx[4];
    size_t gidx = ((size_t)b << 12) + pos;
    float4 p;
    p.x = x - 0.5f * dx; p.z = x + 0.5f * dx;   // 0.5*dx exact -> contraction-safe
    p.y = y - 0.5f * dy; p.w = y + 0.5f * dy;
    P[gidx] = p;
    AR[gidx] = dx * dy;
    topS[gidx] = unorderable((u32)(key >> 32));
    wmax = fmaxf(wmax, fmaxf(dx, dy));
  }
#pragma unroll
  for (int d = 32; d > 0; d >>= 1) wmax = fmaxf(wmax, __shfl_xor(wmax, d, 64));
  if (lane == 0 && wmax > 0.0f)
    atomicMax(&maxWG[b], __float_as_uint(wmax));         // positive-float bits: monotone
}

// WIDE threat precompute: for each box i, find all j < i with IoU > 0.7.
// Each block builds the batch's full spatial hash in LDS (redundantly), then
// each thread scans only in-reach bins (skipped pairs provably inter==0).
// Output: 32B pack per box = u16 cnt + up to 15 u16 threat ids; overflow
// (bin > BCAP2 or cnt > TCAP) -> sentinel cnt=0xFFFF -> exact brute fallback
// in the scan kernel (never hit on bench data).
__global__ __launch_bounds__(256) void threat_kernel(const float4* __restrict__ Pg,
                                                     const float* __restrict__ ARg,
                                                     const u32* __restrict__ maxWG,
                                                     u64* __restrict__ threatPack) {
  __shared__ u16 binL[BINS * BCAP2];
  __shared__ u32 binC[BINS];
  __shared__ u32 ovSh;
  int b = blockIdx.y;
  int tid = threadIdx.x;
  size_t pb = (size_t)b << 12;
  for (int t = tid; t < BINS; t += 256) binC[t] = 0;
  if (tid == 0) ovSh = 0;
  __syncthreads();
  // build the batch hash (all 4096 boxes), 16 inserts per thread
  for (int pass = 0; pass < 16; ++pass) {
    int j = pass * 256 + tid;
    float4 p = Pg[pb + j];
    int bx = bin_coord((p.x + p.z) * 0.5f);
    int by = bin_coord((p.y + p.w) * 0.5f);
    int bin = by * BGRID + bx;
    u32 slot = atomicAdd(&binC[bin], 1u);
    if (slot < BCAP2) binL[bin * BCAP2 + slot] = (u16)j;
    else ovSh = 1;
  }
  __syncthreads();
  int i = blockIdx.x * 256 + tid;                  // this thread's box
  u16 w[16];
#pragma unroll
  for (int e = 0; e < 16; ++e) w[e] = 0;
  if (ovSh) {
    w[0] = 0xFFFFu;                                // sentinel: brute fallback
  } else {
    float4 cp = Pg[pb + i];
    float car = ARg[pb + i];
    float maxW = __uint_as_float(maxWG[b]);
    int rch = (int)ceilf(maxW * 0.25f);            // overlap => bin dist <= rch
    if (rch > BGRID - 1) rch = BGRID - 1;
    int cbx = bin_coord((cp.x + cp.z) * 0.5f);
    int cby = bin_coord((cp.y + cp.w) * 0.5f);
    int x0 = cbx - rch < 0 ? 0 : cbx - rch, x1 = cbx + rch > BGRID - 1 ? BGRID - 1 : cbx + rch;
    int y0 = cby - rch < 0 ? 0 : cby - rch, y1 = cby + rch > BGRID - 1 ? BGRID - 1 : cby + rch;
    int tc = 0; bool over = false;
    for (int yy = y0; yy <= y1; ++yy)
      for (int xx = x0; xx <= x1; ++xx) {
        int bin = yy * BGRID + xx;
        int cnt = (int)binC[bin];
        for (int e = 0; e < cnt; ++e) {
          int j = (int)binL[bin * BCAP2 + e];
          if (j < i) {
            if (iou_pair(Pg[pb + j], ARg[pb + j], cp, car)) {
              if (tc < TCAP) w[1 + tc] = (u16)j, ++tc;
              else over = true;
            }
          }
        }
      }
    w[0] = over ? 0xFFFFu : (u16)tc;
  }
  u64 q0 = (u64)w[0] | ((u64)w[1] << 16) | ((u64)w[2] << 32) | ((u64)w[3] << 48);
  u64 q1 = (u64)w[4] | ((u64)w[5] << 16) | ((u64)w[6] << 32) | ((u64)w[7] << 48);
  u64 q2 = (u64)w[8] | ((u64)w[9] << 16) | ((u64)w[10] << 32) | ((u64)w[11] << 48);
  u64 q3 = (u64)w[12] | ((u64)w[13] << 16) | ((u64)w[14] << 32) | ((u64)w[15] << 48);
  ulonglong2* tp = (ulonglong2*)(threatPack + (pb + (size_t)i) * 4);
  tp[0] = make_ulonglong2(q0, q1);
  tp[1] = make_ulonglong2(q2, q3);
}

// Serial greedy scan over threat lists (1 wave does the scan; 256 threads
// finalize). Zero IoU math on the hot path: lane i is suppressed iff any of
// its threats j is kept — earlier groups via LDS keepFlag, same group via the
// verified ascending-order recurrence. Sentinel packs -> exact brute fallback.
__global__ __launch_bounds__(256, 1) void scan_final_kernel(
    const u64* __restrict__ threatPack,
    const float4* __restrict__ Pg, const float* __restrict__ ARg,
    const float* __restrict__ topS, const u64* __restrict__ selG,
    const float* __restrict__ boxes, const int* __restrict__ labels,
    float* __restrict__ out) {
  __shared__ unsigned char keepFlag[PRE];
  __shared__ u64 kwLDS[64];
  __shared__ int keptIdx[POST];
  __shared__ u32 finSh;
  int b = blockIdx.x;
  int tid = threadIdx.x;
  size_t pb = (size_t)b << 12;
  if (tid < 64) kwLDS[tid] = 0;
  __syncthreads();
  if (tid < 64) {                                  // wave 0: serial scan
    int lane = tid;
    const ulonglong2* tp = (const ulonglong2*)(threatPack + pb * 4);
    ulonglong2 pkA = tp[lane * 2], pkB = tp[lane * 2 + 1];   // group 0 prefetch
    int kn = 0;
    for (int g = 0; g < 64; ++g) {
      ulonglong2 A = pkA, Bv = pkB;
      if (g + 1 < 64) {                            // prefetch next group's packs
        pkA = tp[(g + 1) * 128 + lane * 2];
        pkB = tp[(g + 1) * 128 + lane * 2 + 1];
      }
      int i = g * 64 + lane;
      u32 cnt = (u32)(A.x & 0xFFFFull);
      bool earlySup = false;
      u64 intra = 0;
      if (cnt == 0xFFFFu) {                        // brute fallback (never hit)
        float4 cp = Pg[pb + i]; float car = ARg[pb + i];
        for (int j = 0; j < g * 64; ++j)
          if (keepFlag[j] && iou_pair(Pg[pb + j], ARg[pb + j], cp, car)) earlySup = true;
        for (int j = g * 64; j < i; ++j)
          if (iou_pair(Pg[pb + j], ARg[pb + j], cp, car)) intra |= 1ULL << (j - g * 64);
      } else {
        for (u32 e = 1; e <= cnt; ++e) {
          u64 wq = (e < 4) ? A.x : (e < 8) ? A.y : (e < 12) ? Bv.x : Bv.y;
          int j = (int)((wq >> (16 * (e & 3))) & 0xFFFFull);
          if (j >= g * 64) intra |= 1ULL << (j - g * 64);
          else earlySup |= (keepFlag[j] != 0);
        }
      }
      u64 sup = __ballot(earlySup);
      u64 rem = __ballot(intra != 0ULL);
      while (rem) {                                // ascending: threats j < k final
        int k = __ffsll((long long)rem) - 1;
        rem &= rem - 1;
        if (!((sup >> k) & 1ULL)) {
          u64 mk = readlane64(intra, k);           // bits < k only (j < i)
          if (mk & ~sup) sup |= 1ULL << k;
        }
      }
      u64 keep = ~sup;
      keepFlag[i] = (unsigned char)((keep >> lane) & 1ULL);  // wave-coherent LDS
      if (lane == 0) kwLDS[g] = keep;
      kn += (int)__popcll(keep);
      if (kn >= POST) break;
    }
    // expand keep words into keptIdx (prefix scan over 64 groups)
    u64 kw = kwLDS[lane];
    int cnt = __popcll(kw);
    int pfx = cnt;
#pragma unroll
    for (int d = 1; d < 64; d <<= 1) {
      int up = __shfl_up(pfx, d, 64);
      if (lane >= d) pfx += up;
    }
    int total = __shfl(pfx, 63, 64);
    int pos = pfx - cnt;
    while (kw) {
      int t = __ffsll((long long)kw) - 1;
      kw &= kw - 1;
      if (pos < POST) keptIdx[pos] = (lane << 6) + t;
      ++pos;
    }
    if (lane == 0) finSh = (u32)(total < POST ? total : POST);
  }
  __syncthreads();
  // ---- finalize (all 256 threads): write the 512 output slots ----
  int fin = (int)finSh;
  float* outR = out;
  float* outS = out + BB * POST * 7;
  float* outL = outS + BB * POST;
  for (int s = tid; s < POST; s += 256) {
    int gdx = (b << 9) + s;
    if (s < fin) {
      int i = keptIdx[s];
      u64 key = selG[pb + i];
      u32 n = ~(u32)key;
      size_t src = (size_t)b * NN + n;
      const float* bx = boxes + src * 7;
#pragma unroll
      for (int c = 0; c < 7; ++c) outR[(size_t)gdx * 7 + c] = bx[c];
      outS[gdx] = topS[pb + i];
      outL[gdx] = (float)(labels[src] + 1);
    } else {                                       // empty slots: 0 / 0 / label 1
#pragma unroll
      for (int c = 0; c < 7; ++c) outR[(size_t)gdx * 7 + c] = 0.0f;
      outS[gdx] = 0.0f;
      outL[gdx] = 1.0f;
    }
  }
}

extern "C" void kernel_launch(void* const* d_in, const int* in_sizes, int n_in,
                              void* d_out, int out_size, void* d_ws, size_t ws_size,
                              hipStream_t stream) {
  const float* boxes = (const float*)d_in[0];   // (4,32768,7)
  const float* cls   = (const float*)d_in[1];   // (4,32768,3)
  float* out = (float*)d_out;

  // ---- workspace carve-up (~3 MB) ----
  char* p = (char*)d_ws;
  auto take = [&](size_t bytes) { char* r = p; p += (bytes + 255) & ~(size_t)255; return (void*)r; };
  u64*   keys    = (u64*)  take((size_t)BB * NN * 8);
  int*   labels  = (int*)  take((size_t)BB * NN * 4);
  u32*   histP   = (u32*)  take((size_t)BB * 32 * 2048 * 4);   // per-block partials
  u32*   selinfo = (u32*)  take((size_t)BB * 2 * 4);
  u32*   sfxBuf  = (u32*)  take((size_t)BB * 2048 * 4);
  u32*   cursor  = (u32*)  take((size_t)BB * 2048 * 4);
  u32*   cnt_mid = (u32*)  take((size_t)BB * 4);
  u32*   maxWG   = (u32*)  take((size_t)BB * 4);
  u64*   sel     = (u64*)  take((size_t)BB * PRE * 8);
  u64*   mid     = (u64*)  take((size_t)BB * MIDCAP * 8);
  float4* Pg     = (float4*)take((size_t)BB * PRE * 16);
  float* ARg     = (float*)take((size_t)BB * PRE * 4);
  float* topS    = (float*)take((size_t)BB * PRE * 4);
  u64*   threatP = (u64*)  take((size_t)BB * PRE * 32);

  score_hist_kernel<<<BB * NN / 1024, 256, 0, stream>>>(cls, labels, keys, histP);
  select_kernel<<<BB, 256, 0, stream>>>(histP, selinfo, sfxBuf, cursor, cnt_mid, maxWG);
  compact_kernel<<<BB * NN / 1024, 256, 0, stream>>>(keys, selinfo, cursor, sel, mid, cnt_mid);
  bsort_kernel<<<BB * 2048, 64, 0, stream>>>(sel, mid, sfxBuf, selinfo, cnt_mid,
                                             boxes, Pg, ARg, topS, maxWG);
  threat_kernel<<<dim3(16, BB), 256, 0, stream>>>(Pg, ARg, maxWG, threatP);
  scan_final_kernel<<<BB, 256, 0, stream>>>(threatP, Pg, ARg, topS, sel, boxes, labels, out);
}